// Round 7
// baseline (56.310 us; speedup 1.0000x reference)
//
#include <hip/hip_runtime.h>
#include <hip/hip_bf16.h>
#include <math.h>

#define NROWS 8192
#define MCOLS 8192
#define DK    64
#define TILE_G 8   // column-tiles per block

typedef _Float16 f16x8 __attribute__((ext_vector_type(8)));
typedef __attribute__((ext_vector_type(8))) short bf16x8;
typedef __attribute__((ext_vector_type(4))) float f32x4;

// ws layout: Xf@0 (1MB fp16, FRAGMENT-MAJOR: frag f = ((c*2+ks)*64+lane)*16B,
// c=row/16, lane=(row&15)|((k/8&3)<<4)), Zf@1M same layout over Z rows,
// hx@2M (8192 f32 = 0.5*|Xs'|^2 from ROUNDED values), hz@2M+32K (incl -log2(sf))
#define WS_XH 0u
#define WS_ZH (1u << 20)
#define WS_HX (2u << 20)
#define WS_HZ ((2u << 20) + 32768u)
#define WS_NEED ((size_t)(2u << 20) + 65536u)

#define SQRT_L2E 1.2011224087864498f   // sqrt(log2(e))

__device__ __forceinline__ float softplus_f(float x) {
    // matches jnp.where(x > 36, x, log1p(exp(min(x, 36))))
    return x > 36.0f ? x : log1pf(expf(fminf(x, 36.0f)));
}

// ---------------- prep: scale by w*sqrt(log2e), round fp16, norms -----------
// Panels pre-scaled so MFMA accumulates cross*log2e; norms from the SAME
// rounded fp16 values so dist is exact in fp32; hz absorbs -log2(sigma_f).
// Output panels are written in MFMA-fragment-major layout so the main kernel
// loads each fragment as one contiguous 1KB wave transaction from L2.
__global__ void rbf_prep(const float* __restrict__ X, const float* __restrict__ Z,
                         const float* __restrict__ lraw, const float* __restrict__ sraw,
                         char* __restrict__ ws) {
    __shared__ float wsc[DK];
    if (threadIdx.x < DK)
        wsc[threadIdx.x] = SQRT_L2E / softplus_f(lraw[threadIdx.x]);
    __syncthreads();

    int tid = blockIdx.x * 256 + threadIdx.x;   // 0..131071
    bool isZ = tid >= 65536;                    // wave-uniform
    int t = tid & 65535;
    int row = t >> 3;
    int kc = t & 7;                             // k-chunk of 8
    const float* src = (isZ ? Z : X) + (size_t)row * DK + kc * 8;
    float4 v0 = *(const float4*)(src);
    float4 v1 = *(const float4*)(src + 4);
    float f[8] = {v0.x, v0.y, v0.z, v0.w, v1.x, v1.y, v1.z, v1.w};
    f16x8 hv;
    float sq = 0.0f;
    #pragma unroll
    for (int j = 0; j < 8; ++j) {
        _Float16 h = (_Float16)(f[j] * wsc[kc * 8 + j]);
        hv[j] = h;
        float hf = (float)h;
        sq += hf * hf;
    }
    sq += __shfl_xor(sq, 1);
    sq += __shfl_xor(sq, 2);
    sq += __shfl_xor(sq, 4);
    // fragment-major write: frag (c, ks), lane = (row&15) | ((kc&3)<<4)
    {
        int c  = row >> 4;
        int ks = kc >> 2;
        int lif = (row & 15) | ((kc & 3) << 4);
        *(f16x8*)(ws + (isZ ? WS_ZH : WS_XH)
                  + ((size_t)((c * 2 + ks) * 64 + lif) << 4)) = hv;
    }
    if (kc == 0) {
        float* nrm = (float*)(ws + (isZ ? WS_HZ : WS_HX));
        float v = 0.5f * sq;
        if (isZ) v -= log2f(softplus_f(sraw[0]));   // fold sigma_f into hz
        nrm[row] = v;
    }
}

// ---------------- main: NO LDS, NO barriers ---------------------------------
// Each wave independently computes 32x64 output tiles, loading MFMA fragments
// straight from the fragment-major L2-resident panels (1KB contiguous per
// fragment load). Removes the per-tile barrier + vmcnt(0) store-queue drain
// of the LDS version: stores now issue continuously, fill-kernel style.
__launch_bounds__(512, 4)
__global__ void rbf_main(const char* __restrict__ ws, float* __restrict__ out) {
    // 512 blocks: XCD-bijective swizzle; XCD x owns a contiguous 1024-row band
    // -> its Xf slice (128KB) + all Zf (1MB) stay L2-resident.
    int bid = blockIdx.x;
    int s = (bid & 7) * 64 + (bid >> 3);
    int tR = s >> 3;                  // 0..63 row-tile (128 rows)
    int cg = s & 7;                   // 0..7 col-group (tiles cg*8 .. +8)

    const int tid  = threadIdx.x;
    const int lane = tid & 63;
    const int wid  = tid >> 6;
    const int wr = wid >> 1, wc = wid & 1;
    const int lr = lane & 15, lg = lane >> 4;

    const char* Xf = ws + WS_XH;
    const char* Zf = ws + WS_ZH;
    const float* hx = (const float*)(ws + WS_HX);
    const float* hz = (const float*)(ws + WS_HZ);

    // A fragments: loaded once, reused for all 8 tiles
    f16x8 af[2][2];
    #pragma unroll
    for (int ks = 0; ks < 2; ++ks)
        #pragma unroll
        for (int mi = 0; mi < 2; ++mi) {
            int cx = tR * 8 + wr * 2 + mi;
            af[ks][mi] = *(const f16x8*)(Xf + ((size_t)((cx * 2 + ks) * 64 + lane) << 4));
        }

    float4 hxa[2];
    #pragma unroll
    for (int mi = 0; mi < 2; ++mi)
        hxa[mi] = *(const float4*)(hx + tR * 128 + wr * 32 + mi * 16 + lg * 4);

    for (int g = 0; g < TILE_G; ++g) {
        const int tC = cg * TILE_G + g;

        // Z fragments for this tile: 8 x 1KB contiguous wave loads (L2-hit)
        f16x8 bfr[2][4];
        #pragma unroll
        for (int ks = 0; ks < 2; ++ks)
            #pragma unroll
            for (int ni = 0; ni < 4; ++ni) {
                int cz = tC * 8 + wc * 4 + ni;
                bfr[ks][ni] = *(const f16x8*)(Zf + ((size_t)((cz * 2 + ks) * 64 + lane) << 4));
            }

        f32x4 acc[2][4];
        #pragma unroll
        for (int a = 0; a < 2; ++a)
            #pragma unroll
            for (int b = 0; b < 4; ++b) acc[a][b] = f32x4{0.f, 0.f, 0.f, 0.f};
        #pragma unroll
        for (int ks = 0; ks < 2; ++ks)
            #pragma unroll
            for (int mi = 0; mi < 2; ++mi)
                #pragma unroll
                for (int ni = 0; ni < 4; ++ni)
                    acc[mi][ni] = __builtin_amdgcn_mfma_f32_16x16x32_f16(
                        af[ks][mi], bfr[ks][ni], acc[mi][ni], 0, 0, 0);

        // ---- epilogue: out = exp2(acc - hx' - hz') (R6's measured-best) ----
        float hzv[4];
        #pragma unroll
        for (int ni = 0; ni < 4; ++ni)
            hzv[ni] = hz[tC * 128 + wc * 64 + ni * 16 + lr];
        #pragma unroll
        for (int mi = 0; mi < 2; ++mi) {
            int grow0 = tR * 128 + wr * 32 + mi * 16 + lg * 4;
            #pragma unroll
            for (int ni = 0; ni < 4; ++ni) {
                int gcol = tC * 128 + wc * 64 + ni * 16 + lr;
                size_t obase = (size_t)grow0 * MCOLS + gcol;
                #pragma unroll
                for (int j = 0; j < 4; ++j) {
                    float arg = acc[mi][ni][j] - hxa[mi][j] - hzv[ni];
                    out[obase + (size_t)j * MCOLS] = __builtin_amdgcn_exp2f(arg);
                }
            }
        }
    }
}

// ---------------- fallback (R2 kernel, bf16 hi/lo) if ws too small ----------
__launch_bounds__(512, 4)
__global__ void rbf_fused(const float* __restrict__ X, const float* __restrict__ Z,
                          const float* __restrict__ lraw, const float* __restrict__ sraw,
                          float* __restrict__ out) {
    __shared__ __align__(16) char smem[65536];
    __shared__ float hxz[256];
    __shared__ float wsc[DK];
    __shared__ float sigf_s;

    const int tid = threadIdx.x;
    const int tR = blockIdx.y;
    const int tC = blockIdx.x;

    if (tid < DK) wsc[tid] = 1.0f / softplus_f(lraw[tid]);
    if (tid == 511) sigf_s = softplus_f(sraw[0]);
    __syncthreads();

    #pragma unroll
    for (int i = 0; i < 4; ++i) {
        int rfull = i * 64 + (tid >> 3);
        int r = rfull & 127;
        int kc = tid & 7;
        bool isB = rfull >= 128;
        const float* src = isB ? (Z + (size_t)(tC * 128 + r) * DK + kc * 8)
                               : (X + (size_t)(tR * 128 + r) * DK + kc * 8);
        float4 v0 = *(const float4*)(src);
        float4 v1 = *(const float4*)(src + 4);
        float f[8] = {v0.x, v0.y, v0.z, v0.w, v1.x, v1.y, v1.z, v1.w};
        bf16x8 hv, lv;
        float sq = 0.0f;
        #pragma unroll
        for (int j = 0; j < 8; ++j) {
            float fv = f[j] * wsc[kc * 8 + j];
            sq += fv * fv;
            unsigned int u = __float_as_uint(fv);
            u += 0x7fffu + ((u >> 16) & 1u);
            unsigned short h = (unsigned short)(u >> 16);
            hv[j] = (short)h;
            float hf = __uint_as_float(((unsigned int)h) << 16);
            unsigned int u2 = __float_as_uint(fv - hf);
            u2 += 0x7fffu + ((u2 >> 16) & 1u);
            lv[j] = (short)(unsigned short)(u2 >> 16);
        }
        sq += __shfl_xor(sq, 1);
        sq += __shfl_xor(sq, 2);
        sq += __shfl_xor(sq, 4);
        if (kc == 0) hxz[rfull] = 0.5f * sq;
        int halfOff = isB ? 32768 : 0;
        int byteOff = r * 128 + ((kc * 16) ^ ((r & 7) << 4));
        *(bf16x8*)(smem + halfOff + byteOff) = hv;
        *(bf16x8*)(smem + halfOff + 16384 + byteOff) = lv;
    }
    __syncthreads();

    const int lane = tid & 63;
    const int wid  = tid >> 6;
    const int wr = wid >> 1;
    const int wc = wid & 1;
    const int lr = lane & 15;
    const int lg = lane >> 4;
    const int swz = (lr & 7) << 4;

    f32x4 acc[2][4];
    #pragma unroll
    for (int a = 0; a < 2; ++a)
        #pragma unroll
        for (int b = 0; b < 4; ++b) acc[a][b] = f32x4{0.f, 0.f, 0.f, 0.f};

    #pragma unroll
    for (int pass = 0; pass < 3; ++pass) {
        const char* Ap = smem + ((pass == 2) ? 16384 : 0);
        const char* Bp = smem + 32768 + ((pass == 1) ? 16384 : 0);
        #pragma unroll
        for (int ks = 0; ks < 2; ++ks) {
            int kb = ((lg * 16 + ks * 64) ^ swz);
            bf16x8 af[2], bfr[4];
            #pragma unroll
            for (int mi = 0; mi < 2; ++mi)
                af[mi] = *(const bf16x8*)(Ap + (wr * 32 + mi * 16 + lr) * 128 + kb);
            #pragma unroll
            for (int ni = 0; ni < 4; ++ni)
                bfr[ni] = *(const bf16x8*)(Bp + (wc * 64 + ni * 16 + lr) * 128 + kb);
            #pragma unroll
            for (int mi = 0; mi < 2; ++mi)
                #pragma unroll
                for (int ni = 0; ni < 4; ++ni)
                    acc[mi][ni] = __builtin_amdgcn_mfma_f32_16x16x32_bf16(
                        af[mi], bfr[ni], acc[mi][ni], 0, 0, 0);
        }
    }

    const float sf = sigf_s;
    #pragma unroll
    for (int mi = 0; mi < 2; ++mi) {
        int row0 = wr * 32 + mi * 16 + lg * 4;
        #pragma unroll
        for (int ni = 0; ni < 4; ++ni) {
            int col = wc * 64 + ni * 16 + lr;
            float hzv = hxz[128 + col];
            size_t obase = (size_t)(tR * 128 + row0) * MCOLS + (size_t)(tC * 128 + col);
            #pragma unroll
            for (int j = 0; j < 4; ++j) {
                float arg = acc[mi][ni][j] - (hxz[row0 + j] + hzv);
                out[obase + (size_t)j * MCOLS] = sf * __expf(arg);
            }
        }
    }
}

extern "C" void kernel_launch(void* const* d_in, const int* in_sizes, int n_in,
                              void* d_out, int out_size, void* d_ws, size_t ws_size,
                              hipStream_t stream) {
    const float* X = (const float*)d_in[0];
    const float* Z = (const float*)d_in[1];
    const float* l = (const float*)d_in[2];
    const float* s = (const float*)d_in[3];
    float* out = (float*)d_out;
    if (ws_size >= WS_NEED && d_ws != nullptr) {
        char* ws = (char*)d_ws;
        rbf_prep<<<512, 256, 0, stream>>>(X, Z, l, s, ws);
        rbf_main<<<512, 512, 0, stream>>>(ws, out);
    } else {
        dim3 grid(MCOLS / 128, NROWS / 128);
        rbf_fused<<<grid, dim3(512), 0, stream>>>(X, Z, l, s, out);
    }
}

// Round 8
// 53.364 us; speedup vs baseline: 1.0552x; 1.0552x over previous
//
#include <hip/hip_runtime.h>
#include <hip/hip_bf16.h>
#include <math.h>

#define NROWS 8192
#define MCOLS 8192
#define DK    64
#define TILE_G 8   // column-tiles per block

typedef _Float16 f16x8 __attribute__((ext_vector_type(8)));
typedef __attribute__((ext_vector_type(8))) short bf16x8;
typedef __attribute__((ext_vector_type(4))) float f32x4;

// ws layout: Xh@0 (1MB fp16 [8192][64], scaled by w*sqrt(log2e)), Zh@1M,
// hx@2M (8192 f32 = 0.5*|Xs'|^2 from ROUNDED values), hz@2M+32K (incl -log2(sf))
#define WS_XH 0u
#define WS_ZH (1u << 20)
#define WS_HX (2u << 20)
#define WS_HZ ((2u << 20) + 32768u)
#define WS_NEED ((size_t)(2u << 20) + 65536u)

#define SQRT_L2E 1.2011224087864498f   // sqrt(log2(e))

__device__ __forceinline__ float softplus_f(float x) {
    // matches jnp.where(x > 36, x, log1p(exp(min(x, 36))))
    return x > 36.0f ? x : log1pf(expf(fminf(x, 36.0f)));
}

// LDS-only barrier: drains ds ops (lgkmcnt) but leaves the vmem store queue
// in flight across the barrier (vs __syncthreads' vmcnt(0) drain). The only
// cross-wave dependency at our tile boundary is the Z-panel ds_write.
__device__ __forceinline__ void barrier_lds_only() {
    asm volatile("s_waitcnt lgkmcnt(0)" ::: "memory");
    __builtin_amdgcn_s_barrier();
}

// ---------------- prep: scale by w*sqrt(log2e), round fp16, norms -----------
// Panels pre-scaled so MFMA accumulates cross*log2e; norms from the SAME
// rounded fp16 values so dist is exact in fp32; hz absorbs -log2(sigma_f).
__global__ void rbf_prep(const float* __restrict__ X, const float* __restrict__ Z,
                         const float* __restrict__ lraw, const float* __restrict__ sraw,
                         char* __restrict__ ws) {
    __shared__ float wsc[DK];
    if (threadIdx.x < DK)
        wsc[threadIdx.x] = SQRT_L2E / softplus_f(lraw[threadIdx.x]);
    __syncthreads();

    int tid = blockIdx.x * 256 + threadIdx.x;   // 0..131071
    bool isZ = tid >= 65536;                    // wave-uniform
    int t = tid & 65535;
    int row = t >> 3;
    int kc = t & 7;
    const float* src = (isZ ? Z : X) + (size_t)row * DK + kc * 8;
    float4 v0 = *(const float4*)(src);
    float4 v1 = *(const float4*)(src + 4);
    float f[8] = {v0.x, v0.y, v0.z, v0.w, v1.x, v1.y, v1.z, v1.w};
    f16x8 hv;
    float sq = 0.0f;
    #pragma unroll
    for (int j = 0; j < 8; ++j) {
        _Float16 h = (_Float16)(f[j] * wsc[kc * 8 + j]);
        hv[j] = h;
        float hf = (float)h;
        sq += hf * hf;
    }
    sq += __shfl_xor(sq, 1);
    sq += __shfl_xor(sq, 2);
    sq += __shfl_xor(sq, 4);
    *(f16x8*)(ws + (isZ ? WS_ZH : WS_XH) + (size_t)row * 128 + kc * 16) = hv;
    if (kc == 0) {
        float* nrm = (float*)(ws + (isZ ? WS_HZ : WS_HX));
        float v = 0.5f * sq;
        if (isZ) v -= log2f(softplus_f(sraw[0]));   // fold sigma_f into hz
        nrm[row] = v;
    }
}

// ---------------- main: block = 1 row-tile x 8 col-tiles (R6 structure) -----
// X panel staged once, X fragments hoisted to registers for all 8 tiles.
// Z panel double-buffered in LDS: prefetch loads issued at loop top (OLDER
// than the epilogue stores in the vmcnt FIFO), ds_write after the epilogue,
// then an LDS-ONLY barrier -> epilogue stores pipeline across tiles.
__launch_bounds__(512, 4)
__global__ void rbf_main(const char* __restrict__ ws, float* __restrict__ out) {
    // LDS: X[16K) Z0[16K,32K) Z1[32K,48K); XOR swizzle (row&7)<<4 on byte off
    __shared__ __align__(16) char smem[49152];

    // 512 blocks: XCD-bijective swizzle (8 XCDs x 64 contiguous)
    int bid = blockIdx.x;
    int s = (bid & 7) * 64 + (bid >> 3);
    int tR = s >> 3;                  // 0..63 row-tile
    int cg = s & 7;                   // 0..7 col-group (tiles cg*8 .. +8)

    const int tid  = threadIdx.x;
    const int lane = tid & 63;
    const int wid  = tid >> 6;
    const int wr = wid >> 1, wc = wid & 1;
    const int lr = lane & 15, lg = lane >> 4;
    const int swz = (lr & 7) << 4;

    // per-thread staging slots: 2 x 16B covering a 16KB panel
    const int o0 = tid * 16, o1 = tid * 16 + 8192;
    const int r0 = o0 >> 7, cb0 = o0 & 127;
    const int r1 = o1 >> 7, cb1 = o1 & 127;
    const int d0 = r0 * 128 + (cb0 ^ ((r0 & 7) << 4));
    const int d1 = r1 * 128 + (cb1 ^ ((r1 & 7) << 4));

    // ---- prologue: stage X panel + Z panel of first tile ----
    {
        const char* xsrc = ws + WS_XH + (size_t)tR * 16384;
        *(float4*)(smem + d0) = *(const float4*)(xsrc + o0);
        *(float4*)(smem + d1) = *(const float4*)(xsrc + o1);
        const char* zsrc = ws + WS_ZH + (size_t)(cg * TILE_G) * 16384;
        *(float4*)(smem + 16384 + d0) = *(const float4*)(zsrc + o0);
        *(float4*)(smem + 16384 + d1) = *(const float4*)(zsrc + o1);
    }
    __syncthreads();

    // X fragments -> registers, reused across all 8 tiles
    f16x8 xf[2][2];
    #pragma unroll
    for (int ks = 0; ks < 2; ++ks)
        #pragma unroll
        for (int mi = 0; mi < 2; ++mi)
            xf[ks][mi] = *(const f16x8*)(smem + (wr * 32 + mi * 16 + lr) * 128
                                         + ((lg * 16 + ks * 64) ^ swz));

    // row norms: fixed per thread across tiles
    const float* hx = (const float*)(ws + WS_HX);
    const float* hz = (const float*)(ws + WS_HZ);
    float4 hxa[2];
    #pragma unroll
    for (int mi = 0; mi < 2; ++mi)
        hxa[mi] = *(const float4*)(hx + tR * 128 + wr * 32 + mi * 16 + lg * 4);

    for (int g = 0; g < TILE_G; ++g) {
        const int cur = g & 1;
        const int tC = cg * TILE_G + g;

        // prefetch next Z panel into registers (issued before this tile's
        // stores -> older in the vmcnt FIFO; ds_write's wait leaves stores
        // in flight)
        float4 z0, z1;
        if (g + 1 < TILE_G) {
            const char* zsrc = ws + WS_ZH + (size_t)(tC + 1) * 16384;
            z0 = *(const float4*)(zsrc + o0);
            z1 = *(const float4*)(zsrc + o1);
        }

        // ---- MFMA for tile g ----
        const char* zb = smem + 16384 + cur * 16384;
        f32x4 acc[2][4];
        #pragma unroll
        for (int a = 0; a < 2; ++a)
            #pragma unroll
            for (int b = 0; b < 4; ++b) acc[a][b] = f32x4{0.f, 0.f, 0.f, 0.f};
        #pragma unroll
        for (int ks = 0; ks < 2; ++ks) {
            const int kb = ((lg * 16 + ks * 64) ^ swz);
            f16x8 bfr[4];
            #pragma unroll
            for (int ni = 0; ni < 4; ++ni)
                bfr[ni] = *(const f16x8*)(zb + (wc * 64 + ni * 16 + lr) * 128 + kb);
            #pragma unroll
            for (int mi = 0; mi < 2; ++mi)
                #pragma unroll
                for (int ni = 0; ni < 4; ++ni)
                    acc[mi][ni] = __builtin_amdgcn_mfma_f32_16x16x32_f16(
                        xf[ks][mi], bfr[ni], acc[mi][ni], 0, 0, 0);
        }

        // ---- epilogue: out = exp2(acc - hx' - hz') ----
        float hzv[4];
        #pragma unroll
        for (int ni = 0; ni < 4; ++ni)
            hzv[ni] = hz[tC * 128 + wc * 64 + ni * 16 + lr];
        #pragma unroll
        for (int mi = 0; mi < 2; ++mi) {
            int grow0 = tR * 128 + wr * 32 + mi * 16 + lg * 4;
            #pragma unroll
            for (int ni = 0; ni < 4; ++ni) {
                int gcol = tC * 128 + wc * 64 + ni * 16 + lr;
                size_t obase = (size_t)grow0 * MCOLS + gcol;
                #pragma unroll
                for (int j = 0; j < 4; ++j) {
                    float arg = acc[mi][ni][j] - hxa[mi][j] - hzv[ni];
                    out[obase + (size_t)j * MCOLS] = __builtin_amdgcn_exp2f(arg);
                }
            }
        }

        // ---- rotate Z buffer: LDS-only barrier (stores keep flying) ----
        if (g + 1 < TILE_G) {
            char* zn = smem + 16384 + (1 - cur) * 16384;
            *(float4*)(zn + d0) = z0;
            *(float4*)(zn + d1) = z1;
            barrier_lds_only();
        }
    }
}

// ---------------- fallback (R2 kernel, bf16 hi/lo) if ws too small ----------
__launch_bounds__(512, 4)
__global__ void rbf_fused(const float* __restrict__ X, const float* __restrict__ Z,
                          const float* __restrict__ lraw, const float* __restrict__ sraw,
                          float* __restrict__ out) {
    __shared__ __align__(16) char smem[65536];
    __shared__ float hxz[256];
    __shared__ float wsc[DK];
    __shared__ float sigf_s;

    const int tid = threadIdx.x;
    const int tR = blockIdx.y;
    const int tC = blockIdx.x;

    if (tid < DK) wsc[tid] = 1.0f / softplus_f(lraw[tid]);
    if (tid == 511) sigf_s = softplus_f(sraw[0]);
    __syncthreads();

    #pragma unroll
    for (int i = 0; i < 4; ++i) {
        int rfull = i * 64 + (tid >> 3);
        int r = rfull & 127;
        int kc = tid & 7;
        bool isB = rfull >= 128;
        const float* src = isB ? (Z + (size_t)(tC * 128 + r) * DK + kc * 8)
                               : (X + (size_t)(tR * 128 + r) * DK + kc * 8);
        float4 v0 = *(const float4*)(src);
        float4 v1 = *(const float4*)(src + 4);
        float f[8] = {v0.x, v0.y, v0.z, v0.w, v1.x, v1.y, v1.z, v1.w};
        bf16x8 hv, lv;
        float sq = 0.0f;
        #pragma unroll
        for (int j = 0; j < 8; ++j) {
            float fv = f[j] * wsc[kc * 8 + j];
            sq += fv * fv;
            unsigned int u = __float_as_uint(fv);
            u += 0x7fffu + ((u >> 16) & 1u);
            unsigned short h = (unsigned short)(u >> 16);
            hv[j] = (short)h;
            float hf = __uint_as_float(((unsigned int)h) << 16);
            unsigned int u2 = __float_as_uint(fv - hf);
            u2 += 0x7fffu + ((u2 >> 16) & 1u);
            lv[j] = (short)(unsigned short)(u2 >> 16);
        }
        sq += __shfl_xor(sq, 1);
        sq += __shfl_xor(sq, 2);
        sq += __shfl_xor(sq, 4);
        if (kc == 0) hxz[rfull] = 0.5f * sq;
        int halfOff = isB ? 32768 : 0;
        int byteOff = r * 128 + ((kc * 16) ^ ((r & 7) << 4));
        *(bf16x8*)(smem + halfOff + byteOff) = hv;
        *(bf16x8*)(smem + halfOff + 16384 + byteOff) = lv;
    }
    __syncthreads();

    const int lane = tid & 63;
    const int wid  = tid >> 6;
    const int wr = wid >> 1;
    const int wc = wid & 1;
    const int lr = lane & 15;
    const int lg = lane >> 4;
    const int swz = (lr & 7) << 4;

    f32x4 acc[2][4];
    #pragma unroll
    for (int a = 0; a < 2; ++a)
        #pragma unroll
        for (int b = 0; b < 4; ++b) acc[a][b] = f32x4{0.f, 0.f, 0.f, 0.f};

    #pragma unroll
    for (int pass = 0; pass < 3; ++pass) {
        const char* Ap = smem + ((pass == 2) ? 16384 : 0);
        const char* Bp = smem + 32768 + ((pass == 1) ? 16384 : 0);
        #pragma unroll
        for (int ks = 0; ks < 2; ++ks) {
            int kb = ((lg * 16 + ks * 64) ^ swz);
            bf16x8 af[2], bfr[4];
            #pragma unroll
            for (int mi = 0; mi < 2; ++mi)
                af[mi] = *(const bf16x8*)(Ap + (wr * 32 + mi * 16 + lr) * 128 + kb);
            #pragma unroll
            for (int ni = 0; ni < 4; ++ni)
                bfr[ni] = *(const bf16x8*)(Bp + (wc * 64 + ni * 16 + lr) * 128 + kb);
            #pragma unroll
            for (int mi = 0; mi < 2; ++mi)
                #pragma unroll
                for (int ni = 0; ni < 4; ++ni)
                    acc[mi][ni] = __builtin_amdgcn_mfma_f32_16x16x32_bf16(
                        af[mi], bfr[ni], acc[mi][ni], 0, 0, 0);
        }
    }

    const float sf = sigf_s;
    #pragma unroll
    for (int mi = 0; mi < 2; ++mi) {
        int row0 = wr * 32 + mi * 16 + lg * 4;
        #pragma unroll
        for (int ni = 0; ni < 4; ++ni) {
            int col = wc * 64 + ni * 16 + lr;
            float hzv = hxz[128 + col];
            size_t obase = (size_t)(tR * 128 + row0) * MCOLS + (size_t)(tC * 128 + col);
            #pragma unroll
            for (int j = 0; j < 4; ++j) {
                float arg = acc[mi][ni][j] - (hxz[row0 + j] + hzv);
                out[obase + (size_t)j * MCOLS] = sf * __expf(arg);
            }
        }
    }
}

extern "C" void kernel_launch(void* const* d_in, const int* in_sizes, int n_in,
                              void* d_out, int out_size, void* d_ws, size_t ws_size,
                              hipStream_t stream) {
    const float* X = (const float*)d_in[0];
    const float* Z = (const float*)d_in[1];
    const float* l = (const float*)d_in[2];
    const float* s = (const float*)d_in[3];
    float* out = (float*)d_out;
    if (ws_size >= WS_NEED && d_ws != nullptr) {
        char* ws = (char*)d_ws;
        rbf_prep<<<512, 256, 0, stream>>>(X, Z, l, s, ws);
        rbf_main<<<512, 512, 0, stream>>>(ws, out);
    } else {
        dim3 grid(MCOLS / 128, NROWS / 128);
        rbf_fused<<<grid, dim3(512), 0, stream>>>(X, Z, l, s, out);
    }
}